// Round 14
// baseline (218.930 us; speedup 1.0000x reference)
//
#include <hip/hip_runtime.h>
#include <math.h>

#define G      1708
#define GP     1728         // padded per-head row stride
#define C4     427          // float4 chunks per row
#define NH     5
#define NB     16
#define NC     34
#define JSL    16           // j-slices per i-group
#define ITR    2            // i per thread
#define IPB    32           // i per block = (256/JSL)*ITR
#define ICH    54           // ceil(G/IPB)
#define LN_EPS 1e-6f
#define LOG2E  1.4426950408889634f

typedef float vf2 __attribute__((ext_vector_type(2)));

// ---------------------------------------------------------------------------
// attn_layer: r6-proven structure (grid (54,5,16)=4320, JSL=16, ITR=2,
// packed-asm phase C measured 45.8us) with ONE change: phase A/B keep the
// combined heads in registers (r9-proven) instead of an hrow LDS buffer ->
// LDS 20.9KB -> ~14.1KB -> 8 blocks/CU (wave cap) instead of 7.  Occupancy
// is the measured lever (r1: 8/CU + 62-65% occ = fastest attn at 43.8us).
// ---------------------------------------------------------------------------
template <bool FIRST>
__global__ __launch_bounds__(256, 8) void attn_layer(
    const float* __restrict__ hprev, const float* __restrict__ php,
    const float* __restrict__ lna, const float* __restrict__ lnb,
    const float* __restrict__ WQ, const float* __restrict__ WK,
    const float* __restrict__ WV, const float* __restrict__ W0,
    float* __restrict__ ph, float* __restrict__ hcur)
{
    __shared__ __align__(16) float krow[G];
    __shared__ __align__(16) float vrow[G];
    __shared__ float hqs[IPB];
    __shared__ float red[16];

    const int ic = blockIdx.x, h = blockIdx.y, b = blockIdx.z;
    const int tid = threadIdx.x;
    const int base = ic * IPB;

    const float4* hp4 = reinterpret_cast<const float4*>(hprev + (size_t)b * G);
    float4* kr4 = reinterpret_cast<float4*>(krow);
    float4* vr4 = reinterpret_cast<float4*>(vrow);
    const float2* kr2 = reinterpret_cast<const float2*>(krow);
    const float2* vr2 = reinterpret_cast<const float2*>(vrow);

    // ---- phase A: combine heads (registers) + LN stats ----
    float4 acc0, acc1;
    float mean = 0.f, inv = 0.f;
    if constexpr (!FIRST) {
        const float4* p0 = reinterpret_cast<const float4*>(php + ((size_t)b * NH + 0) * GP);
        const float4* p1 = reinterpret_cast<const float4*>(php + ((size_t)b * NH + 1) * GP);
        const float4* p2 = reinterpret_cast<const float4*>(php + ((size_t)b * NH + 2) * GP);
        const float4* p3 = reinterpret_cast<const float4*>(php + ((size_t)b * NH + 3) * GP);
        const float4* p4 = reinterpret_cast<const float4*>(php + ((size_t)b * NH + 4) * GP);
        float s = 0.f, ss = 0.f;
        {   // it = 0: c = tid < 256 <= C4, no guard
            const int c = tid;
            float4 a = p0[c], t;
            t = p1[c]; a.x += t.x; a.y += t.y; a.z += t.z; a.w += t.w;
            t = p2[c]; a.x += t.x; a.y += t.y; a.z += t.z; a.w += t.w;
            t = p3[c]; a.x += t.x; a.y += t.y; a.z += t.z; a.w += t.w;
            t = p4[c]; a.x += t.x; a.y += t.y; a.z += t.z; a.w += t.w;
            acc0 = a;
            s  += (a.x + a.y) + (a.z + a.w);
            ss += (a.x * a.x + a.y * a.y) + (a.z * a.z + a.w * a.w);
        }
        {   // it = 1
            const int c = tid + 256;
            if (c < C4) {
                float4 a = p0[c], t;
                t = p1[c]; a.x += t.x; a.y += t.y; a.z += t.z; a.w += t.w;
                t = p2[c]; a.x += t.x; a.y += t.y; a.z += t.z; a.w += t.w;
                t = p3[c]; a.x += t.x; a.y += t.y; a.z += t.z; a.w += t.w;
                t = p4[c]; a.x += t.x; a.y += t.y; a.z += t.z; a.w += t.w;
                acc1 = a;
                s  += (a.x + a.y) + (a.z + a.w);
                ss += (a.x * a.x + a.y * a.y) + (a.z * a.z + a.w * a.w);
            }
        }
        for (int o = 1; o < 64; o <<= 1) {
            s  += __shfl_xor(s, o);
            ss += __shfl_xor(ss, o);
        }
        if ((tid & 63) == 0) { red[tid >> 6] = s; red[4 + (tid >> 6)] = ss; }
        __syncthreads();
        float S  = (red[0] + red[1]) + (red[2] + red[3]);
        float SS = (red[4] + red[5]) + (red[6] + red[7]);
        mean = S / (float)G;
        float var = fmaxf((SS - S * mean) / (float)(G - 1), 0.f);
        inv = 1.f / (sqrtf(var) + LN_EPS);
    }

    // ---- phase B: h values (regs), k/v tables in LDS, block kmin/kmax ----
    const float4* ga4 = reinterpret_cast<const float4*>(lna);
    const float4* gb4 = reinterpret_cast<const float4*>(lnb);
    const float4* wk4 = reinterpret_cast<const float4*>(WK + (size_t)h * G);
    const float4* wv4 = reinterpret_cast<const float4*>(WV + (size_t)h * G);
    float4* hc4 = (!FIRST && hcur != nullptr && h == 0 && ic == 0)
                      ? reinterpret_cast<float4*>(hcur + (size_t)b * G) : nullptr;

    float kmx = -INFINITY, kmn = INFINITY;
#pragma unroll
    for (int it = 0; it < 2; ++it) {
        const int c = tid + it * 256;
        if (it == 0 || c < C4) {
            float4 hv;
            if constexpr (FIRST) {
                hv = hp4[c];
            } else {
                float4 a = (it == 0) ? acc0 : acc1;
                float4 hp = hp4[c], ga = ga4[c], gb = gb4[c];
                hv.x = hp.x + ga.x * (a.x - mean) * inv + gb.x;
                hv.y = hp.y + ga.y * (a.y - mean) * inv + gb.y;
                hv.z = hp.z + ga.z * (a.z - mean) * inv + gb.z;
                hv.w = hp.w + ga.w * (a.w - mean) * inv + gb.w;
            }
            if (hc4) hc4[c] = hv;
            float4 wk = wk4[c], wv = wv4[c], kl, vv;
            kl.x = hv.x * wk.x * LOG2E; kl.y = hv.y * wk.y * LOG2E;
            kl.z = hv.z * wk.z * LOG2E; kl.w = hv.w * wk.w * LOG2E;
            vv.x = hv.x * wv.x; vv.y = hv.y * wv.y;
            vv.z = hv.z * wv.z; vv.w = hv.w * wv.w;
            kr4[c] = kl;
            vr4[c] = vv;
            kmx = fmaxf(kmx, fmaxf(fmaxf(kl.x, kl.y), fmaxf(kl.z, kl.w)));
            kmn = fminf(kmn, fminf(fminf(kl.x, kl.y), fminf(kl.z, kl.w)));
            // stash the h values this block needs for q
            const int r0 = (c << 2) - base;
            if (r0 >= -3 && r0 < IPB) {
                if ((unsigned)r0       < (unsigned)IPB) hqs[r0]     = hv.x;
                if ((unsigned)(r0 + 1) < (unsigned)IPB) hqs[r0 + 1] = hv.y;
                if ((unsigned)(r0 + 2) < (unsigned)IPB) hqs[r0 + 2] = hv.z;
                if ((unsigned)(r0 + 3) < (unsigned)IPB) hqs[r0 + 3] = hv.w;
            }
        }
    }
    for (int o = 1; o < 64; o <<= 1) {
        kmx = fmaxf(kmx, __shfl_xor(kmx, o));
        kmn = fminf(kmn, __shfl_xor(kmn, o));
    }
    if ((tid & 63) == 0) { red[8 + (tid >> 6)] = kmx; red[12 + (tid >> 6)] = kmn; }
    __syncthreads();   // k/v/hqs tables + red[8..15] visible
    kmx = fmaxf(fmaxf(red[8], red[9]),  fmaxf(red[10], red[11]));
    kmn = fminf(fminf(red[12], red[13]), fminf(red[14], red[15]));

    // ---- phase C: softmax-weighted sums over j (r6 packed fp32, 45.8us) ---
    const int ig = tid >> 4, sl = tid & 15;
    const int i0 = base + ig * ITR;          // even
    const bool valid = i0 < G;               // G even
    const int is = valid ? i0 : base;        // base row always < G and stashed

    const float hq0 = hqs[is - base], hq1 = hqs[is - base + 1];
    const float2 wq = *reinterpret_cast<const float2*>(WQ + (size_t)h * G + is);
    float q[ITR] = {hq0 * wq.x, hq1 * wq.y};
    float nm[ITR];
    vf2 q2[ITR], nm2[ITR], s1p[ITR], s2p[ITR];
#pragma unroll
    for (int r = 0; r < ITR; ++r) {
        nm[r] = -fmaxf(q[r] * kmx, q[r] * kmn);   // exact rank-1 row max
        q2[r].x = q[r];  q2[r].y = q[r];
        nm2[r].x = nm[r]; nm2[r].y = nm[r];
        s1p[r].x = 0.f; s1p[r].y = 0.f;
        s2p[r].x = 0.f; s2p[r].y = 0.f;
    }

#pragma unroll 2
    for (int c = sl; c < C4; c += JSL) {
        float4 kk = kr4[c];
        float4 vq = vr4[c];
        vf2 kxy, kzw, vxy, vzw;
        kxy.x = kk.x; kxy.y = kk.y; kzw.x = kk.z; kzw.y = kk.w;
        vxy.x = vq.x; vxy.y = vq.y; vzw.x = vq.z; vzw.y = vq.w;
#pragma unroll
        for (int r = 0; r < ITR; ++r) {
            vf2 a0, a1, e0, e1;
            asm("v_pk_fma_f32 %0, %1, %2, %3"
                : "=v"(a0) : "v"(q2[r]), "v"(kxy), "v"(nm2[r]));
            asm("v_pk_fma_f32 %0, %1, %2, %3"
                : "=v"(a1) : "v"(q2[r]), "v"(kzw), "v"(nm2[r]));
            e0.x = __builtin_amdgcn_exp2f(a0.x);
            e0.y = __builtin_amdgcn_exp2f(a0.y);
            e1.x = __builtin_amdgcn_exp2f(a1.x);
            e1.y = __builtin_amdgcn_exp2f(a1.y);
            asm("v_pk_add_f32 %0, %0, %1" : "+v"(s1p[r]) : "v"(e0));
            asm("v_pk_fma_f32 %0, %1, %2, %0" : "+v"(s2p[r]) : "v"(e0), "v"(vxy));
            asm("v_pk_add_f32 %0, %0, %1" : "+v"(s1p[r]) : "v"(e1));
            asm("v_pk_fma_f32 %0, %1, %2, %0" : "+v"(s2p[r]) : "v"(e1), "v"(vzw));
        }
    }

    float S1[ITR], S2[ITR];
#pragma unroll
    for (int r = 0; r < ITR; ++r) {
        S1[r] = s1p[r].x + s1p[r].y;
        S2[r] = s2p[r].x + s2p[r].y;
        S1[r] += __shfl_xor(S1[r], 1);
        S1[r] += __shfl_xor(S1[r], 2);
        S1[r] += __shfl_xor(S1[r], 4);
        S1[r] += __shfl_xor(S1[r], 8);
        S2[r] += __shfl_xor(S2[r], 1);
        S2[r] += __shfl_xor(S2[r], 2);
        S2[r] += __shfl_xor(S2[r], 4);
        S2[r] += __shfl_xor(S2[r], 8);
    }

    if (sl == 0 && valid) {
        const float w0h = W0[h];
        const float2 kt2 = kr2[i0 >> 1];
        const float2 vt2 = vr2[i0 >> 1];
        const float kli[ITR] = {kt2.x, kt2.y};
        const float vvi[ITR] = {vt2.x, vt2.y};
        float o[ITR];
#pragma unroll
        for (int r = 0; r < ITR; ++r) {
            float eii = __builtin_amdgcn_exp2f(fmaf(q[r], kli[r], nm[r]));
            o[r] = w0h * (S2[r] - eii * vvi[r]) / S1[r];
        }
        *reinterpret_cast<float2*>(ph + ((size_t)b * NH + h) * GP + i0) =
            make_float2(o[0], o[1]);
    }
}

// ---------------------------------------------------------------------------
// tail_kernel: one block per batch row (r2-proven).  Recombine layer-3 heads
// + LN + residual -> h3, 34 wave-parallel fc dots, log_softmax.
// ---------------------------------------------------------------------------
__global__ __launch_bounds__(256) void tail_kernel(
    const float* __restrict__ hprev, const float* __restrict__ php,
    const float* __restrict__ lna, const float* __restrict__ lnb,
    const float* __restrict__ fcw, const float* __restrict__ fcb,
    float* __restrict__ out)
{
    __shared__ __align__(16) float hrow[G];
    __shared__ float red[8];
    __shared__ float lg[NC];
    const int b = blockIdx.x, tid = threadIdx.x;

    const float4* p0 = reinterpret_cast<const float4*>(php + ((size_t)b * NH + 0) * GP);
    const float4* p1 = reinterpret_cast<const float4*>(php + ((size_t)b * NH + 1) * GP);
    const float4* p2 = reinterpret_cast<const float4*>(php + ((size_t)b * NH + 2) * GP);
    const float4* p3 = reinterpret_cast<const float4*>(php + ((size_t)b * NH + 3) * GP);
    const float4* p4 = reinterpret_cast<const float4*>(php + ((size_t)b * NH + 4) * GP);
    float4* hr4 = reinterpret_cast<float4*>(hrow);

    float s = 0.f, ss = 0.f;
    for (int c = tid; c < C4; c += 256) {
        float4 a = p0[c], t;
        t = p1[c]; a.x += t.x; a.y += t.y; a.z += t.z; a.w += t.w;
        t = p2[c]; a.x += t.x; a.y += t.y; a.z += t.z; a.w += t.w;
        t = p3[c]; a.x += t.x; a.y += t.y; a.z += t.z; a.w += t.w;
        t = p4[c]; a.x += t.x; a.y += t.y; a.z += t.z; a.w += t.w;
        hr4[c] = a;
        s  += (a.x + a.y) + (a.z + a.w);
        ss += (a.x * a.x + a.y * a.y) + (a.z * a.z + a.w * a.w);
    }
    for (int o = 1; o < 64; o <<= 1) {
        s  += __shfl_xor(s, o);
        ss += __shfl_xor(ss, o);
    }
    if ((tid & 63) == 0) { red[tid >> 6] = s; red[4 + (tid >> 6)] = ss; }
    __syncthreads();
    float S  = (red[0] + red[1]) + (red[2] + red[3]);
    float SS = (red[4] + red[5]) + (red[6] + red[7]);
    const float mean = S / (float)G;
    const float var  = fmaxf((SS - S * mean) / (float)(G - 1), 0.f);
    const float inv  = 1.f / (sqrtf(var) + LN_EPS);

    const float4* hp4 = reinterpret_cast<const float4*>(hprev + (size_t)b * G);
    const float4* ga4 = reinterpret_cast<const float4*>(lna);
    const float4* gb4 = reinterpret_cast<const float4*>(lnb);
    for (int c = tid; c < C4; c += 256) {
        float4 a = hr4[c], hp = hp4[c], ga = ga4[c], gb = gb4[c], hv;
        hv.x = hp.x + ga.x * (a.x - mean) * inv + gb.x;
        hv.y = hp.y + ga.y * (a.y - mean) * inv + gb.y;
        hv.z = hp.z + ga.z * (a.z - mean) * inv + gb.z;
        hv.w = hp.w + ga.w * (a.w - mean) * inv + gb.w;
        hr4[c] = hv;
    }
    __syncthreads();

    const int wid = tid >> 6, lane = tid & 63;
    for (int c = wid; c < NC; c += 4) {
        const float4* w4 = reinterpret_cast<const float4*>(fcw + (size_t)c * G);
        float acc = 0.f;
        for (int k = lane; k < C4; k += 64) {
            float4 hh = hr4[k], w = w4[k];
            acc += (hh.x * w.x + hh.y * w.y) + (hh.z * w.z + hh.w * w.w);
        }
        for (int o = 1; o < 64; o <<= 1) acc += __shfl_xor(acc, o);
        if (lane == 0) lg[c] = acc + fcb[c];
    }
    __syncthreads();

    if (tid < 64) {
        float l = (tid < NC) ? lg[tid] : -INFINITY;
        float mm = l;
        for (int o = 32; o; o >>= 1) mm = fmaxf(mm, __shfl_xor(mm, o));
        float e = (tid < NC) ? expf(l - mm) : 0.f;
        float se = e;
        for (int o = 32; o; o >>= 1) se += __shfl_xor(se, o);
        if (tid < NC) out[(size_t)b * NC + tid] = l - mm - logf(se);
    }
}

// ---------------------------------------------------------------------------
extern "C" void kernel_launch(void* const* d_in, const int* in_sizes, int n_in,
                              void* d_out, int out_size, void* d_ws, size_t ws_size,
                              hipStream_t stream)
{
    const float* x    = (const float*)d_in[0];
    const float* WQ1  = (const float*)d_in[1];
    const float* WK1  = (const float*)d_in[2];
    const float* WV1  = (const float*)d_in[3];
    const float* W01  = (const float*)d_in[4];
    const float* WQ2  = (const float*)d_in[5];
    const float* WK2  = (const float*)d_in[6];
    const float* WV2  = (const float*)d_in[7];
    const float* W02  = (const float*)d_in[8];
    const float* WQ3  = (const float*)d_in[9];
    const float* WK3  = (const float*)d_in[10];
    const float* WV3  = (const float*)d_in[11];
    const float* W03  = (const float*)d_in[12];
    const float* lna  = (const float*)d_in[13];
    const float* lnb  = (const float*)d_in[14];
    const float* fcw  = (const float*)d_in[15];
    const float* fcb  = (const float*)d_in[16];
    float* out = (float*)d_out;

    const size_t PHS = (size_t)NB * NH * GP;
    float* pha = (float*)d_ws;           // layer 1 / 3 per-head rows
    float* phb = pha + PHS;              // layer 2 per-head rows
    float* h1  = phb + PHS;              // [NB,G]  (combined input of layer 3)
    float* h2  = h1 + (size_t)NB * G;    // [NB,G]  (combined input of tail LN)

    const dim3 agrid(ICH, NH, NB);       // (54,5,16) = 4320 blocks

    attn_layer<true><<<agrid, 256, 0, stream>>>(
        x, nullptr, lna, lnb, WQ1, WK1, WV1, W01, pha, nullptr);
    attn_layer<false><<<agrid, 256, 0, stream>>>(
        x, pha, lna, lnb, WQ2, WK2, WV2, W02, phb, h1);
    attn_layer<false><<<agrid, 256, 0, stream>>>(
        h1, phb, lna, lnb, WQ3, WK3, WV3, W03, pha, h2);
    tail_kernel<<<NB, 256, 0, stream>>>(
        h2, pha, lna, lnb, fcw, fcb, out);
}

// Round 15
// 200.522 us; speedup vs baseline: 1.0918x; 1.0918x over previous
//
#include <hip/hip_runtime.h>
#include <math.h>

#define G      1708
#define GP     1728         // padded per-head row stride
#define C4     427          // float4 chunks per row
#define NH     5
#define NB     16
#define NC     34
#define JSL    16           // j-slices per i-group
#define ITR    2            // i per thread
#define IPB    32           // i per block = (256/JSL)*ITR
#define ICH    54           // ceil(G/IPB)
#define LN_EPS 1e-6f
#define LOG2E  1.4426950408889634f

typedef float vf2 __attribute__((ext_vector_type(2)));

// ---------------------------------------------------------------------------
// attn_layer: r14-measured best (44.7us/dispatch, VGPR 20, LDS 14.3KB,
// 8 blocks/CU).  Phase A/B keep combined heads in registers; phase C is the
// r6 packed-asm loop.  Byte-identical to r14.
// ---------------------------------------------------------------------------
template <bool FIRST>
__global__ __launch_bounds__(256, 8) void attn_layer(
    const float* __restrict__ hprev, const float* __restrict__ php,
    const float* __restrict__ lna, const float* __restrict__ lnb,
    const float* __restrict__ WQ, const float* __restrict__ WK,
    const float* __restrict__ WV, const float* __restrict__ W0,
    float* __restrict__ ph, float* __restrict__ hcur)
{
    __shared__ __align__(16) float krow[G];
    __shared__ __align__(16) float vrow[G];
    __shared__ float hqs[IPB];
    __shared__ float red[16];

    const int ic = blockIdx.x, h = blockIdx.y, b = blockIdx.z;
    const int tid = threadIdx.x;
    const int base = ic * IPB;

    const float4* hp4 = reinterpret_cast<const float4*>(hprev + (size_t)b * G);
    float4* kr4 = reinterpret_cast<float4*>(krow);
    float4* vr4 = reinterpret_cast<float4*>(vrow);
    const float2* kr2 = reinterpret_cast<const float2*>(krow);
    const float2* vr2 = reinterpret_cast<const float2*>(vrow);

    // ---- phase A: combine heads (registers) + LN stats ----
    float4 acc0, acc1;
    float mean = 0.f, inv = 0.f;
    if constexpr (!FIRST) {
        const float4* p0 = reinterpret_cast<const float4*>(php + ((size_t)b * NH + 0) * GP);
        const float4* p1 = reinterpret_cast<const float4*>(php + ((size_t)b * NH + 1) * GP);
        const float4* p2 = reinterpret_cast<const float4*>(php + ((size_t)b * NH + 2) * GP);
        const float4* p3 = reinterpret_cast<const float4*>(php + ((size_t)b * NH + 3) * GP);
        const float4* p4 = reinterpret_cast<const float4*>(php + ((size_t)b * NH + 4) * GP);
        float s = 0.f, ss = 0.f;
        {   // it = 0: c = tid < 256 <= C4, no guard
            const int c = tid;
            float4 a = p0[c], t;
            t = p1[c]; a.x += t.x; a.y += t.y; a.z += t.z; a.w += t.w;
            t = p2[c]; a.x += t.x; a.y += t.y; a.z += t.z; a.w += t.w;
            t = p3[c]; a.x += t.x; a.y += t.y; a.z += t.z; a.w += t.w;
            t = p4[c]; a.x += t.x; a.y += t.y; a.z += t.z; a.w += t.w;
            acc0 = a;
            s  += (a.x + a.y) + (a.z + a.w);
            ss += (a.x * a.x + a.y * a.y) + (a.z * a.z + a.w * a.w);
        }
        {   // it = 1
            const int c = tid + 256;
            if (c < C4) {
                float4 a = p0[c], t;
                t = p1[c]; a.x += t.x; a.y += t.y; a.z += t.z; a.w += t.w;
                t = p2[c]; a.x += t.x; a.y += t.y; a.z += t.z; a.w += t.w;
                t = p3[c]; a.x += t.x; a.y += t.y; a.z += t.z; a.w += t.w;
                t = p4[c]; a.x += t.x; a.y += t.y; a.z += t.z; a.w += t.w;
                acc1 = a;
                s  += (a.x + a.y) + (a.z + a.w);
                ss += (a.x * a.x + a.y * a.y) + (a.z * a.z + a.w * a.w);
            }
        }
        for (int o = 1; o < 64; o <<= 1) {
            s  += __shfl_xor(s, o);
            ss += __shfl_xor(ss, o);
        }
        if ((tid & 63) == 0) { red[tid >> 6] = s; red[4 + (tid >> 6)] = ss; }
        __syncthreads();
        float S  = (red[0] + red[1]) + (red[2] + red[3]);
        float SS = (red[4] + red[5]) + (red[6] + red[7]);
        mean = S / (float)G;
        float var = fmaxf((SS - S * mean) / (float)(G - 1), 0.f);
        inv = 1.f / (sqrtf(var) + LN_EPS);
    }

    // ---- phase B: h values (regs), k/v tables in LDS, block kmin/kmax ----
    const float4* ga4 = reinterpret_cast<const float4*>(lna);
    const float4* gb4 = reinterpret_cast<const float4*>(lnb);
    const float4* wk4 = reinterpret_cast<const float4*>(WK + (size_t)h * G);
    const float4* wv4 = reinterpret_cast<const float4*>(WV + (size_t)h * G);
    float4* hc4 = (!FIRST && hcur != nullptr && h == 0 && ic == 0)
                      ? reinterpret_cast<float4*>(hcur + (size_t)b * G) : nullptr;

    float kmx = -INFINITY, kmn = INFINITY;
#pragma unroll
    for (int it = 0; it < 2; ++it) {
        const int c = tid + it * 256;
        if (it == 0 || c < C4) {
            float4 hv;
            if constexpr (FIRST) {
                hv = hp4[c];
            } else {
                float4 a = (it == 0) ? acc0 : acc1;
                float4 hp = hp4[c], ga = ga4[c], gb = gb4[c];
                hv.x = hp.x + ga.x * (a.x - mean) * inv + gb.x;
                hv.y = hp.y + ga.y * (a.y - mean) * inv + gb.y;
                hv.z = hp.z + ga.z * (a.z - mean) * inv + gb.z;
                hv.w = hp.w + ga.w * (a.w - mean) * inv + gb.w;
            }
            if (hc4) hc4[c] = hv;
            float4 wk = wk4[c], wv = wv4[c], kl, vv;
            kl.x = hv.x * wk.x * LOG2E; kl.y = hv.y * wk.y * LOG2E;
            kl.z = hv.z * wk.z * LOG2E; kl.w = hv.w * wk.w * LOG2E;
            vv.x = hv.x * wv.x; vv.y = hv.y * wv.y;
            vv.z = hv.z * wv.z; vv.w = hv.w * wv.w;
            kr4[c] = kl;
            vr4[c] = vv;
            kmx = fmaxf(kmx, fmaxf(fmaxf(kl.x, kl.y), fmaxf(kl.z, kl.w)));
            kmn = fminf(kmn, fminf(fminf(kl.x, kl.y), fminf(kl.z, kl.w)));
            // stash the h values this block needs for q
            const int r0 = (c << 2) - base;
            if (r0 >= -3 && r0 < IPB) {
                if ((unsigned)r0       < (unsigned)IPB) hqs[r0]     = hv.x;
                if ((unsigned)(r0 + 1) < (unsigned)IPB) hqs[r0 + 1] = hv.y;
                if ((unsigned)(r0 + 2) < (unsigned)IPB) hqs[r0 + 2] = hv.z;
                if ((unsigned)(r0 + 3) < (unsigned)IPB) hqs[r0 + 3] = hv.w;
            }
        }
    }
    for (int o = 1; o < 64; o <<= 1) {
        kmx = fmaxf(kmx, __shfl_xor(kmx, o));
        kmn = fminf(kmn, __shfl_xor(kmn, o));
    }
    if ((tid & 63) == 0) { red[8 + (tid >> 6)] = kmx; red[12 + (tid >> 6)] = kmn; }
    __syncthreads();   // k/v/hqs tables + red[8..15] visible
    kmx = fmaxf(fmaxf(red[8], red[9]),  fmaxf(red[10], red[11]));
    kmn = fminf(fminf(red[12], red[13]), fminf(red[14], red[15]));

    // ---- phase C: softmax-weighted sums over j (r6 packed fp32) ----
    const int ig = tid >> 4, sl = tid & 15;
    const int i0 = base + ig * ITR;          // even
    const bool valid = i0 < G;               // G even
    const int is = valid ? i0 : base;        // base row always < G and stashed

    const float hq0 = hqs[is - base], hq1 = hqs[is - base + 1];
    const float2 wq = *reinterpret_cast<const float2*>(WQ + (size_t)h * G + is);
    float q[ITR] = {hq0 * wq.x, hq1 * wq.y};
    float nm[ITR];
    vf2 q2[ITR], nm2[ITR], s1p[ITR], s2p[ITR];
#pragma unroll
    for (int r = 0; r < ITR; ++r) {
        nm[r] = -fmaxf(q[r] * kmx, q[r] * kmn);   // exact rank-1 row max
        q2[r].x = q[r];  q2[r].y = q[r];
        nm2[r].x = nm[r]; nm2[r].y = nm[r];
        s1p[r].x = 0.f; s1p[r].y = 0.f;
        s2p[r].x = 0.f; s2p[r].y = 0.f;
    }

#pragma unroll 2
    for (int c = sl; c < C4; c += JSL) {
        float4 kk = kr4[c];
        float4 vq = vr4[c];
        vf2 kxy, kzw, vxy, vzw;
        kxy.x = kk.x; kxy.y = kk.y; kzw.x = kk.z; kzw.y = kk.w;
        vxy.x = vq.x; vxy.y = vq.y; vzw.x = vq.z; vzw.y = vq.w;
#pragma unroll
        for (int r = 0; r < ITR; ++r) {
            vf2 a0, a1, e0, e1;
            asm("v_pk_fma_f32 %0, %1, %2, %3"
                : "=v"(a0) : "v"(q2[r]), "v"(kxy), "v"(nm2[r]));
            asm("v_pk_fma_f32 %0, %1, %2, %3"
                : "=v"(a1) : "v"(q2[r]), "v"(kzw), "v"(nm2[r]));
            e0.x = __builtin_amdgcn_exp2f(a0.x);
            e0.y = __builtin_amdgcn_exp2f(a0.y);
            e1.x = __builtin_amdgcn_exp2f(a1.x);
            e1.y = __builtin_amdgcn_exp2f(a1.y);
            asm("v_pk_add_f32 %0, %0, %1" : "+v"(s1p[r]) : "v"(e0));
            asm("v_pk_fma_f32 %0, %1, %2, %0" : "+v"(s2p[r]) : "v"(e0), "v"(vxy));
            asm("v_pk_add_f32 %0, %0, %1" : "+v"(s1p[r]) : "v"(e1));
            asm("v_pk_fma_f32 %0, %1, %2, %0" : "+v"(s2p[r]) : "v"(e1), "v"(vzw));
        }
    }

    float S1[ITR], S2[ITR];
#pragma unroll
    for (int r = 0; r < ITR; ++r) {
        S1[r] = s1p[r].x + s1p[r].y;
        S2[r] = s2p[r].x + s2p[r].y;
        S1[r] += __shfl_xor(S1[r], 1);
        S1[r] += __shfl_xor(S1[r], 2);
        S1[r] += __shfl_xor(S1[r], 4);
        S1[r] += __shfl_xor(S1[r], 8);
        S2[r] += __shfl_xor(S2[r], 1);
        S2[r] += __shfl_xor(S2[r], 2);
        S2[r] += __shfl_xor(S2[r], 4);
        S2[r] += __shfl_xor(S2[r], 8);
    }

    if (sl == 0 && valid) {
        const float w0h = W0[h];
        const float2 kt2 = kr2[i0 >> 1];
        const float2 vt2 = vr2[i0 >> 1];
        const float kli[ITR] = {kt2.x, kt2.y};
        const float vvi[ITR] = {vt2.x, vt2.y};
        float o[ITR];
#pragma unroll
        for (int r = 0; r < ITR; ++r) {
            float eii = __builtin_amdgcn_exp2f(fmaf(q[r], kli[r], nm[r]));
            o[r] = w0h * (S2[r] - eii * vvi[r]) / S1[r];
        }
        *reinterpret_cast<float2*>(ph + ((size_t)b * NH + h) * GP + i0) =
            make_float2(o[0], o[1]);
    }
}

// ---------------------------------------------------------------------------
// One logit per block: recombine layer-3 heads + LN on the fly, dot with
// fc row c.  grid (NC, NB) = 544 blocks.  (r0/r6-proven ~5us path)
// ---------------------------------------------------------------------------
__global__ __launch_bounds__(256) void logits_kernel(
    const float* __restrict__ hprev, const float* __restrict__ php,
    const float* __restrict__ lna, const float* __restrict__ lnb,
    const float* __restrict__ fcw, const float* __restrict__ fcb,
    float* __restrict__ lgt)
{
    __shared__ __align__(16) float arow[G];
    __shared__ float red[8];
    const int c = blockIdx.x, b = blockIdx.y, tid = threadIdx.x;

    const float4* p0 = reinterpret_cast<const float4*>(php + ((size_t)b * NH + 0) * GP);
    const float4* p1 = reinterpret_cast<const float4*>(php + ((size_t)b * NH + 1) * GP);
    const float4* p2 = reinterpret_cast<const float4*>(php + ((size_t)b * NH + 2) * GP);
    const float4* p3 = reinterpret_cast<const float4*>(php + ((size_t)b * NH + 3) * GP);
    const float4* p4 = reinterpret_cast<const float4*>(php + ((size_t)b * NH + 4) * GP);
    float4* ar4 = reinterpret_cast<float4*>(arow);

    float s = 0.f, ss = 0.f;
    for (int k = tid; k < C4; k += 256) {
        float4 a = p0[k], t;
        t = p1[k]; a.x += t.x; a.y += t.y; a.z += t.z; a.w += t.w;
        t = p2[k]; a.x += t.x; a.y += t.y; a.z += t.z; a.w += t.w;
        t = p3[k]; a.x += t.x; a.y += t.y; a.z += t.z; a.w += t.w;
        t = p4[k]; a.x += t.x; a.y += t.y; a.z += t.z; a.w += t.w;
        ar4[k] = a;
        s  += (a.x + a.y) + (a.z + a.w);
        ss += (a.x * a.x + a.y * a.y) + (a.z * a.z + a.w * a.w);
    }
    for (int o = 1; o < 64; o <<= 1) {
        s  += __shfl_xor(s, o);
        ss += __shfl_xor(ss, o);
    }
    if ((tid & 63) == 0) { red[tid >> 6] = s; red[4 + (tid >> 6)] = ss; }
    __syncthreads();
    float S  = (red[0] + red[1]) + (red[2] + red[3]);
    float SS = (red[4] + red[5]) + (red[6] + red[7]);
    const float mean = S / (float)G;
    const float var  = fmaxf((SS - S * mean) / (float)(G - 1), 0.f);
    const float inv  = 1.f / (sqrtf(var) + LN_EPS);

    const float4* hp4 = reinterpret_cast<const float4*>(hprev + (size_t)b * G);
    const float4* ga4 = reinterpret_cast<const float4*>(lna);
    const float4* gb4 = reinterpret_cast<const float4*>(lnb);
    const float4* w4  = reinterpret_cast<const float4*>(fcw + (size_t)c * G);
    float acc = 0.f;
    for (int k = tid; k < C4; k += 256) {
        float4 a = ar4[k], hp = hp4[k], ga = ga4[k], gb = gb4[k], w = w4[k];
        float hx = hp.x + ga.x * (a.x - mean) * inv + gb.x;
        float hy = hp.y + ga.y * (a.y - mean) * inv + gb.y;
        float hz = hp.z + ga.z * (a.z - mean) * inv + gb.z;
        float hw = hp.w + ga.w * (a.w - mean) * inv + gb.w;
        acc += (hx * w.x + hy * w.y) + (hz * w.z + hw * w.w);
    }
    for (int o = 1; o < 64; o <<= 1) acc += __shfl_xor(acc, o);
    __syncthreads();
    if ((tid & 63) == 0) red[tid >> 6] = acc;
    __syncthreads();
    if (tid == 0)
        lgt[(size_t)b * NC + c] =
            (red[0] + red[1]) + (red[2] + red[3]) + fcb[c];
}

// out = log_softmax(logits) — one wave per batch row  (r0/r6-proven)
__global__ __launch_bounds__(64) void lsm_kernel(
    const float* __restrict__ lgt, float* __restrict__ out)
{
    const int b = blockIdx.x, tid = threadIdx.x;
    float l = (tid < NC) ? lgt[(size_t)b * NC + tid] : -INFINITY;
    float mm = l;
    for (int o = 32; o; o >>= 1) mm = fmaxf(mm, __shfl_xor(mm, o));
    float e = (tid < NC) ? expf(l - mm) : 0.f;
    float se = e;
    for (int o = 32; o; o >>= 1) se += __shfl_xor(se, o);
    if (tid < NC) out[(size_t)b * NC + tid] = l - mm - logf(se);
}

// ---------------------------------------------------------------------------
extern "C" void kernel_launch(void* const* d_in, const int* in_sizes, int n_in,
                              void* d_out, int out_size, void* d_ws, size_t ws_size,
                              hipStream_t stream)
{
    const float* x    = (const float*)d_in[0];
    const float* WQ1  = (const float*)d_in[1];
    const float* WK1  = (const float*)d_in[2];
    const float* WV1  = (const float*)d_in[3];
    const float* W01  = (const float*)d_in[4];
    const float* WQ2  = (const float*)d_in[5];
    const float* WK2  = (const float*)d_in[6];
    const float* WV2  = (const float*)d_in[7];
    const float* W02  = (const float*)d_in[8];
    const float* WQ3  = (const float*)d_in[9];
    const float* WK3  = (const float*)d_in[10];
    const float* WV3  = (const float*)d_in[11];
    const float* W03  = (const float*)d_in[12];
    const float* lna  = (const float*)d_in[13];
    const float* lnb  = (const float*)d_in[14];
    const float* fcw  = (const float*)d_in[15];
    const float* fcb  = (const float*)d_in[16];
    float* out = (float*)d_out;

    const size_t PHS = (size_t)NB * NH * GP;
    float* pha = (float*)d_ws;           // layer 1 / 3 per-head rows
    float* phb = pha + PHS;              // layer 2 per-head rows
    float* h1  = phb + PHS;              // [NB,G]  (combined input of layer 3)
    float* h2  = h1 + (size_t)NB * G;    // [NB,G]  (combined input of logits LN)
    float* lgt = h2 + (size_t)NB * G;    // [NB,NC]

    const dim3 agrid(ICH, NH, NB);       // (54,5,16) = 4320 blocks

    attn_layer<true><<<agrid, 256, 0, stream>>>(
        x, nullptr, lna, lnb, WQ1, WK1, WV1, W01, pha, nullptr);
    attn_layer<false><<<agrid, 256, 0, stream>>>(
        x, pha, lna, lnb, WQ2, WK2, WV2, W02, phb, h1);
    attn_layer<false><<<agrid, 256, 0, stream>>>(
        h1, phb, lna, lnb, WQ3, WK3, WV3, W03, pha, h2);
    logits_kernel<<<dim3(NC, NB), 256, 0, stream>>>(
        h2, pha, lna, lnb, fcw, fcb, lgt);
    lsm_kernel<<<NB, 64, 0, stream>>>(lgt, out);
}